// Round 4
// baseline (250.716 us; speedup 1.0000x reference)
//
#include <hip/hip_runtime.h>
#include <hip/hip_bf16.h>

// LinearAttention: B=4 N=4096 D=1024 H=16 DH=64
// Pipeline:
//  1. convert x -> bf16 ; transpose-convert Wq/Wk/Wv -> Wt[3072][1024] (B^T), Wo -> WoT
//  2. gemm256<0>: qkv = x @ [Wq|Wk|Wv]  (256x256 tile, BK=64, 8 waves, 8-phase counted-vmcnt
//     schedule, 128KiB LDS, T2 swizzle, T5 setprio). elu+1 on q,k; LDS-staged epilogue:
//       q -> [bh][n][d], k,v -> [bh][d][n]
//  3. ksum partials; kv partials (fp32) + combine
//  4. attn = (q @ kv) / (q . ksum + eps)
//  5. gemm256<1>: out = attn @ Wo + bo (fp32, two-half-pass LDS epilogue)

#define DEV_INLINE __device__ __forceinline__

typedef short bf16x8 __attribute__((ext_vector_type(8)));
typedef float f32x4  __attribute__((ext_vector_type(4)));

static constexpr int Bb = 4, Nn = 4096, Dd = 1024, Hh = 16, DHd = 64;
static constexpr int Mrows = Bb * Nn;   // 16384

DEV_INLINE float bf2f(short s) {
  unsigned u = ((unsigned)(unsigned short)s) << 16;
  float f; __builtin_memcpy(&f, &u, 4); return f;
}
DEV_INLINE short f2bf(float f) {
  unsigned u; __builtin_memcpy(&u, &f, 4);
  unsigned r = (u + 0x7fffu + ((u >> 16) & 1u)) >> 16;
  return (short)r;
}

DEV_INLINE void gload16(const void* g, void* l) {
  typedef __attribute__((address_space(1))) const void gv_t;
  typedef __attribute__((address_space(3))) void lv_t;
  __builtin_amdgcn_global_load_lds((gv_t*)g, (lv_t*)l, 16, 0, 0);
}

#define SBAR() __builtin_amdgcn_s_barrier()
#define WAITV(n) asm volatile("s_waitcnt vmcnt(" #n ")" ::: "memory")

// ---------------- 1. conversions ----------------

__global__ void convert_x_kernel(const float* __restrict__ x, short* __restrict__ xb) {
  const int total = Mrows * 1024 / 4;
  for (int i = blockIdx.x * 256 + threadIdx.x; i < total; i += 2048 * 256) {
    float4 v = ((const float4*)x)[i];
    short4 o;
    o.x = f2bf(v.x); o.y = f2bf(v.y); o.z = f2bf(v.z); o.w = f2bf(v.w);
    ((short4*)xb)[i] = o;
  }
}

// W: [1024][1024] fp32 row-major [k][n] -> Wt: [n][k] bf16 ; z selects which W
__global__ void transposeW_kernel(const float* __restrict__ Wq, const float* __restrict__ Wk,
                                  const float* __restrict__ Wv, const float* __restrict__ Wo,
                                  short* __restrict__ Wt, short* __restrict__ WoT) {
  int z = blockIdx.z;
  const float* W = (z == 0) ? Wq : (z == 1) ? Wk : (z == 2) ? Wv : Wo;
  short* dstb = (z < 3) ? (Wt + (size_t)z * 1024 * 1024) : WoT;
  __shared__ float tile[64][69];
  int t = threadIdx.x;
  int r = t >> 2, c4 = (t & 3) << 4;
  const float* src = W + (blockIdx.y * 64 + r) * 1024 + blockIdx.x * 64 + c4;
  for (int j = 0; j < 4; ++j) {
    float4 v = ((const float4*)src)[j];
    tile[r][c4 + 4 * j + 0] = v.x;
    tile[r][c4 + 4 * j + 1] = v.y;
    tile[r][c4 + 4 * j + 2] = v.z;
    tile[r][c4 + 4 * j + 3] = v.w;
  }
  __syncthreads();
  __attribute__((aligned(16))) short tmp[16];
  for (int j = 0; j < 16; ++j) tmp[j] = f2bf(tile[c4 + j][r]);
  short* dst = dstb + (blockIdx.x * 64 + r) * 1024 + blockIdx.y * 64 + c4;
  ((int4*)dst)[0] = ((int4*)tmp)[0];
  ((int4*)dst)[1] = ((int4*)tmp)[1];
}

// ---------------- 2/5. 256x256 BK=64 8-phase MFMA GEMM ----------------
// 8 waves (2M x 4N), 512 threads, 128 KiB LDS: [set][A|B][256 rows][64 bf16],
// rows 128B, slot(16B) swizzled by row&7. Stage = gload_lds linear dest +
// pre-swizzled per-lane global source (rule #21). K=1024 fixed.

// stage one half-tile (128 rows x 64 cols): 2 gload_lds per thread
DEV_INLINE void stage_half(const short* __restrict__ gtile, char* smreg, int h) {
  int t = threadIdx.x;
  int lane = t & 63, w = t >> 6;
#pragma unroll
  for (int l = 0; l < 2; ++l) {
    int rbase = h * 128 + l * 64 + w * 8;
    int row = rbase + (lane >> 3);
    int slot = lane & 7;
    gload16(gtile + (size_t)row * 1024 + ((slot ^ (row & 7)) << 3),
            smreg + (size_t)rbase * 128);
  }
}

#define READ_A(set, mbase, kk)                                                     \
  _Pragma("unroll") for (int m_ = 0; m_ < 4; ++m_) {                               \
    int row_ = wr * 128 + ((mbase) + m_) * 16 + rl;                                \
    int slot_ = (kk) * 4 + kg;                                                     \
    a[m_] = *(const bf16x8*)(smraw + (set) * 65536 + row_ * 128 +                  \
                             (((slot_ ^ (row_ & 7))) << 4));                       \
  }

#define READ_B(set, kk)                                                            \
  _Pragma("unroll") for (int n_ = 0; n_ < 4; ++n_) {                               \
    int row_ = wc * 64 + n_ * 16 + rl;                                             \
    int slot_ = (kk) * 4 + kg;                                                     \
    b[n_] = *(const bf16x8*)(smraw + 32768 + (set) * 65536 + row_ * 128 +          \
                             (((slot_ ^ (row_ & 7))) << 4));                       \
  }

#define MF(mbase)                                                                  \
  __builtin_amdgcn_s_setprio(1);                                                   \
  _Pragma("unroll") for (int m_ = 0; m_ < 4; ++m_)                                 \
    _Pragma("unroll") for (int n_ = 0; n_ < 4; ++n_)                               \
      acc[(mbase) + m_][n_] = __builtin_amdgcn_mfma_f32_16x16x32_bf16(             \
          a[m_], b[n_], acc[(mbase) + m_][n_], 0, 0, 0);                           \
  __builtin_amdgcn_s_setprio(0);

template <int MODE>
__global__ __launch_bounds__(512, 2) void gemm256_kernel(
    const short* __restrict__ A, const short* __restrict__ Bt,
    short* __restrict__ q, short* __restrict__ kT, short* __restrict__ vT,
    float* __restrict__ out, const float* __restrict__ bias, int nTilesN) {
  __shared__ __align__(16) char smraw[131072];
  char* smA0 = smraw;
  char* smB0 = smraw + 32768;
  char* smA1 = smraw + 65536;
  char* smB1 = smraw + 98304;

  int bid = blockIdx.x;
  int xcd = bid & 7, lo = bid >> 3;
  int tn = lo >> 3, tmg = lo & 7;
  int tm = xcd * 8 + tmg;

  int t = threadIdx.x, w = t >> 6, lane = t & 63;
  int rl = lane & 15, kg = lane >> 4;
  int wr = w >> 2, wc = w & 3;

  const short* Ab = A + (size_t)tm * 256 * 1024;
  const short* Bb2 = Bt + (size_t)tn * 256 * 1024;

  f32x4 acc[8][4] = {};
  bf16x8 a[4], b[4];

  // prologue: tile0 (set0) fully + tile1's B h0
  stage_half(Ab, smA0, 0);
  stage_half(Ab, smA0, 1);
  stage_half(Bb2, smB0, 0);
  stage_half(Bb2, smB0, 1);
  stage_half(Bb2 + 64, smB1, 0);
  WAITV(2);
  SBAR();

#pragma unroll 1
  for (int i = 0; i < 8; ++i) {
    int k_odd = i * 128 + 64, k_n2 = i * 128 + 128, k_n3 = i * 128 + 192;
    // P1
    READ_A(0, 0, 0); READ_B(0, 0);
    stage_half(Bb2 + k_odd, smB1, 1);
    SBAR(); MF(0); SBAR();
    // P2
    READ_A(0, 4, 0);
    stage_half(Ab + k_odd, smA1, 0);
    SBAR(); MF(4); SBAR();
    // P3
    READ_A(0, 0, 1); READ_B(0, 1);
    stage_half(Ab + k_odd, smA1, 1);
    SBAR(); MF(0); SBAR();
    // P4
    READ_A(0, 4, 1);
    stage_half(Bb2 + k_n2, smB0, 0);
    WAITV(2); SBAR(); MF(4); SBAR();
    // P5
    READ_A(1, 0, 0); READ_B(1, 0);
    stage_half(Ab + k_n2, smA0, 0);
    SBAR(); MF(0); SBAR();
    // P6
    READ_A(1, 4, 0);
    stage_half(Ab + k_n2, smA0, 1);
    SBAR(); MF(4); SBAR();
    // P7
    READ_A(1, 0, 1); READ_B(1, 1);
    stage_half(Bb2 + k_n2, smB0, 1);
    SBAR(); MF(0); SBAR();
    // P8
    READ_A(1, 4, 1);
    stage_half(Bb2 + k_n3, smB1, 0);
    WAITV(2); SBAR(); MF(4); SBAR();
  }

  // drain in-flight (garbage tail) stages before LDS reuse
  WAITV(0);
  SBAR();

  if (MODE == 1) {
    // two 128-row fp32 half-passes; swizzled [128][256] f32 tile (128 KiB)
    float* smf = (float*)smraw;
    for (int hp = 0; hp < 2; ++hp) {
      if (wr == hp) {
#pragma unroll
        for (int m = 0; m < 8; ++m)
#pragma unroll
          for (int n = 0; n < 4; ++n)
#pragma unroll
            for (int r = 0; r < 4; ++r) {
              int lrow = m * 16 + kg * 4 + r;
              int col = wc * 64 + n * 16 + rl;
              smf[lrow * 256 + ((((col >> 2) ^ (lrow & 7))) << 2) + (col & 3)] = acc[m][n][r];
            }
      }
      SBAR();
      for (int it = 0; it < 16; ++it) {
        int idx = it * 512 + t;
        int row = idx >> 6, c4 = (idx & 63) << 2;
        float4 v = *(const float4*)&smf[row * 256 + ((((c4 >> 2) ^ (row & 7))) << 2)];
        float4 bv = *(const float4*)&bias[tn * 256 + c4];
        v.x += bv.x; v.y += bv.y; v.z += bv.z; v.w += bv.w;
        *(float4*)&out[(size_t)(tm * 256 + hp * 128 + row) * Dd + tn * 256 + c4] = v;
      }
      SBAR();
    }
    return;
  }

  // MODE 0: stage 256x256 bf16 C tile in LDS (transposed for k/v), coalesced int4 out
  short* smc = (short*)smraw;
  int sec = tn >> 2, tl = tn & 3;   // 0=q 1=k 2=v (4 tn-tiles per section)
#pragma unroll
  for (int m = 0; m < 8; ++m)
#pragma unroll
    for (int n = 0; n < 4; ++n)
#pragma unroll
      for (int r = 0; r < 4; ++r) {
        float v = acc[m][n][r];
        if (sec <= 1) v = v > 0.f ? v + 1.f : __expf(v);   // elu(x)+1
        int row = wr * 128 + m * 16 + kg * 4 + r;
        int col = wc * 64 + n * 16 + rl;
        int rr = (sec == 0) ? row : col;
        int cc = (sec == 0) ? col : row;
        smc[rr * 256 + ((((cc >> 3) ^ (rr & 7))) << 3) + (cc & 7)] = f2bf(v);
      }
  SBAR();
  if (sec == 0) {
    for (int it = 0; it < 16; ++it) {
      int idx = it * 512 + t;
      int row = idx >> 5, c8 = (idx & 31) << 3;
      int4 val = *(const int4*)&smc[row * 256 + ((((c8 >> 3) ^ (row & 7))) << 3)];
      int grow = tm * 256 + row;
      int bI = grow >> 12, n = grow & 4095;
      int g = tl * 256 + c8;
      int h = g >> 6, d0 = g & 63;
      *(int4*)&q[(((size_t)(bI * Hh + h)) * Nn + n) * DHd + d0] = val;
    }
  } else {
    short* dst = (sec == 1) ? kT : vT;
    for (int it = 0; it < 16; ++it) {
      int idx = it * 512 + t;
      int dr = idx >> 5, c8 = (idx & 31) << 3;
      int4 val = *(const int4*)&smc[dr * 256 + ((((c8 >> 3) ^ (dr & 7))) << 3)];
      int g = tl * 256 + dr;
      int h = g >> 6, d = g & 63;
      int grow0 = tm * 256 + c8;
      int bI = grow0 >> 12, n0 = grow0 & 4095;
      *(int4*)&dst[(((size_t)(bI * Hh + h)) * DHd + d) * Nn + n0] = val;
    }
  }
}

// ---------------- 3a. ksum partials: ksp[bh][8][64] ----------------
__global__ void ksum_kernel(const short* __restrict__ kT, float* __restrict__ ksp) {
  int bh = blockIdx.x >> 3, seg = blockIdx.x & 7;
  int t = threadIdx.x;
  int d = t >> 2, sub = t & 3;
  const short* row = kT + ((size_t)bh * DHd + d) * Nn + seg * 512;
  float s = 0.f;
  for (int i = sub * 8; i < 512; i += 32) {
    bf16x8 v = *(const bf16x8*)&row[i];
    for (int j = 0; j < 8; ++j) s += bf2f(v[j]);
  }
  s += __shfl_xor(s, 1);
  s += __shfl_xor(s, 2);
  if (sub == 0) ksp[(bh * 8 + seg) * 64 + d] = s;
}

// ---------------- 3b. kv partials: kvp[bh][4][e][d] fp32 ----------------
__global__ __launch_bounds__(256, 2) void kv_kernel(const short* __restrict__ kT,
                                                    const short* __restrict__ vT,
                                                    float* __restrict__ kvp) {
  __shared__ __align__(16) short smK[64 * 128];
  __shared__ __align__(16) short smV[64 * 128];
  int bh = blockIdx.x, seg = blockIdx.y;
  int t = threadIdx.x;
  int w = t >> 6, lane = t & 63, rl = lane & 15, kg = lane >> 4;
  const short* kb = kT + (size_t)bh * DHd * Nn + seg * 1024;
  const short* vb = vT + (size_t)bh * DHd * Nn + seg * 1024;
  f32x4 acc[4] = {};
  for (int n0 = 0; n0 < 1024; n0 += 128) {
    __syncthreads();
    for (int p = 0; p < 4; ++p) {
      int c = p * 256 + t;
      int row = c >> 4, u = c & 15;
      int off = ((u ^ (row & 15)) << 3);          // pre-swizzled source slot
      gload16(kb + row * Nn + n0 + off, (char*)smK + p * 4096 + w * 1024);
      gload16(vb + row * Nn + n0 + off, (char*)smV + p * 4096 + w * 1024);
    }
    __syncthreads();
    for (int kk = 0; kk < 4; ++kk) {
      int slot = kk * 4 + kg;
      int rowA = w * 16 + rl;
      bf16x8 a = *(const bf16x8*)&smK[rowA * 128 + ((slot ^ (rowA & 15)) << 3)];
      for (int nt = 0; nt < 4; ++nt) {
        int rowB = nt * 16 + rl;
        bf16x8 b = *(const bf16x8*)&smV[rowB * 128 + ((slot ^ (rowB & 15)) << 3)];
        acc[nt] = __builtin_amdgcn_mfma_f32_16x16x32_bf16(a, b, acc[nt], 0, 0, 0);
      }
    }
  }
  // LDS-staged coalesced fp32 output (64x64 tile = 16 KB, reuse smK)
  float* smf = (float*)smK;
  __syncthreads();
  for (int nt = 0; nt < 4; ++nt)
    for (int r = 0; r < 4; ++r)
      smf[(nt * 16 + rl) * 64 + (w * 16 + kg * 4 + r)] = acc[nt][r];
  __syncthreads();
  float* dst = kvp + ((size_t)(bh * 4 + seg)) * 4096;
  for (int i = 0; i < 4; ++i) {
    int idx = i * 256 + t;
    int e = idx >> 4, c4 = (idx & 15) << 2;
    *(float4*)&dst[e * 64 + c4] = *(const float4*)&smf[e * 64 + c4];
  }
}

// combine 4 fp32 partials -> kvT bf16 [bh][e][d]
__global__ void kvc_kernel(const float* __restrict__ kvp, short* __restrict__ kvT) {
  int bh = blockIdx.x, t = threadIdx.x;
  const float* p0 = kvp + (size_t)bh * 4 * 4096;
  for (int rep = 0; rep < 4; ++rep) {
    int idx = rep * 1024 + t * 4;
    float4 a = *(const float4*)&p0[idx];
    float4 b = *(const float4*)&p0[4096 + idx];
    float4 c = *(const float4*)&p0[8192 + idx];
    float4 d = *(const float4*)&p0[12288 + idx];
    short4 o;
    o.x = f2bf(a.x + b.x + c.x + d.x);
    o.y = f2bf(a.y + b.y + c.y + d.y);
    o.z = f2bf(a.z + b.z + c.z + d.z);
    o.w = f2bf(a.w + b.w + c.w + d.w);
    *(short4*)&kvT[(size_t)bh * 4096 + idx] = o;
  }
}

// ---------------- 4. out = (q @ kv) / z ----------------
__global__ __launch_bounds__(256, 2) void attn_kernel(const short* __restrict__ q,
                                                      const short* __restrict__ kvT,
                                                      const float* __restrict__ ksp,
                                                      short* __restrict__ attn) {
  int rb = blockIdx.x, bh = blockIdx.y;
  int b = bh >> 4, h = bh & 15;
  __shared__ float sks[64];
  __shared__ __align__(16) short satt[64 * 64];
  int t = threadIdx.x, w = t >> 6, lane = t & 63, rl = lane & 15, kg = lane >> 4;
  if (t < 64) {
    float s = 0.f;
    for (int j = 0; j < 8; ++j) s += ksp[(bh * 8 + j) * 64 + t];
    sks[t] = s;
  }
  __syncthreads();
  int row0 = rb * 64 + w * 16;
  const short* qb = q + ((size_t)bh * Nn + row0) * DHd;
  const short* kvb = kvT + (size_t)bh * 4096;
  f32x4 acc[4] = {};
  float zp = 0.f;
  for (int kk = 0; kk < 2; ++kk) {
    int kb = kk * 32 + kg * 8;
    bf16x8 a = *(const bf16x8*)&qb[rl * DHd + kb];
    for (int j = 0; j < 8; ++j) zp += bf2f(a[j]) * sks[kb + j];
    for (int nt = 0; nt < 4; ++nt) {
      bf16x8 bfr = *(const bf16x8*)&kvb[(nt * 16 + rl) * 64 + kb];
      acc[nt] = __builtin_amdgcn_mfma_f32_16x16x32_bf16(a, bfr, acc[nt], 0, 0, 0);
    }
  }
  zp += __shfl_xor(zp, 16);
  zp += __shfl_xor(zp, 32);     // every lane now holds z for row (lane&15)
  float zr[4];
  for (int r = 0; r < 4; ++r) zr[r] = __shfl(zp, kg * 4 + r);
  for (int nt = 0; nt < 4; ++nt)
    for (int r = 0; r < 4; ++r)
      satt[(w * 16 + kg * 4 + r) * 64 + nt * 16 + rl] = f2bf(acc[nt][r] / (zr[r] + 1e-6f));
  __syncthreads();
  for (int i = 0; i < 2; ++i) {
    int idx = i * 256 + t;                 // int4 index over 64x64 shorts
    int row = idx >> 3, c8 = (idx & 7) << 3;
    int n = rb * 64 + row;
    *(int4*)&attn[((size_t)(b * Nn + n)) * 1024 + h * 64 + c8] = *(const int4*)&satt[row * 64 + c8];
  }
}

// ---------------- launch ----------------
extern "C" void kernel_launch(void* const* d_in, const int* in_sizes, int n_in,
                              void* d_out, int out_size, void* d_ws, size_t ws_size,
                              hipStream_t stream) {
  const float* x  = (const float*)d_in[0];
  const float* Wq = (const float*)d_in[1];
  const float* Wk = (const float*)d_in[2];
  const float* Wv = (const float*)d_in[3];
  const float* Wo = (const float*)d_in[4];
  const float* bo = (const float*)d_in[5];
  float* out = (float*)d_out;

  char* ws = (char*)d_ws;
  size_t off = 0;
  auto alloc = [&](size_t bytes) {
    char* p = ws + off;
    off += (bytes + 255) & ~(size_t)255;
    return p;
  };
  short* xb   = (short*)alloc((size_t)Mrows * 1024 * 2);     // 32 MB
  short* Wt   = (short*)alloc((size_t)3072 * 1024 * 2);      // 6 MB
  short* WoT  = (short*)alloc((size_t)1024 * 1024 * 2);      // 2 MB
  short* qb   = (short*)alloc((size_t)64 * Nn * DHd * 2);    // 32 MB  [bh][n][d]
  short* kT   = (short*)alloc((size_t)64 * DHd * Nn * 2);    // 32 MB  [bh][d][n]
  short* vT   = (short*)alloc((size_t)64 * DHd * Nn * 2);    // 32 MB  [bh][d][n]
  float* ksp  = (float*)alloc((size_t)64 * 8 * 64 * 4);      // ksum partials
  float* kvp  = (float*)alloc((size_t)64 * 4 * 4096 * 4);    // 4 MB kv partials
  short* kvT  = (short*)alloc((size_t)64 * 4096 * 2);        // [bh][e][d]
  short* attn = (short*)alloc((size_t)Mrows * 1024 * 2);     // 32 MB
  (void)alloc(8192);                                          // pad for benign K over-reads

  convert_x_kernel<<<2048, 256, 0, stream>>>(x, xb);
  transposeW_kernel<<<dim3(16, 16, 4), 256, 0, stream>>>(Wq, Wk, Wv, Wo, Wt, WoT);

  gemm256_kernel<0><<<768, 512, 0, stream>>>(xb, Wt, qb, kT, vT, nullptr, nullptr, 12);
  ksum_kernel<<<512, 256, 0, stream>>>(kT, ksp);
  kv_kernel<<<dim3(64, 4), 256, 0, stream>>>(kT, vT, kvp);
  kvc_kernel<<<64, 256, 0, stream>>>(kvp, kvT);
  attn_kernel<<<dim3(64, 64), 256, 0, stream>>>(qb, kvT, ksp, attn);
  gemm256_kernel<1><<<256, 512, 0, stream>>>(attn, WoT, nullptr, nullptr, nullptr, out, bo, 4);
}

// Round 5
// 235.067 us; speedup vs baseline: 1.0666x; 1.0666x over previous
//
#include <hip/hip_runtime.h>
#include <hip/hip_bf16.h>

// LinearAttention: B=4 N=4096 D=1024 H=16 DH=64
// Pipeline:
//  1. convert x -> bf16 ; transpose-convert Wq/Wk/Wv -> Wt[3072][1024] (B^T), Wo -> WoT (+ zero ksum)
//  2. gemm128<0>: qkv = x @ [Wq|Wk|Wv], elu+1 on q,k; swizzled K-loop LDS; LDS-staged epilogue:
//       q -> [bh][n][d], k,v -> [bh][d][n]; fused ksum atomics from the k-tile
//  3. kv partials (8-way n-split, fp32, LDS-staged out) + combine
//  4. attn = (q @ kv) / (q . ksum + eps), LDS-staged coalesced out
//  5. gemm128<1>: out = attn @ Wo + bo (fp32, LDS-staged coalesced epilogue)

#define DEV_INLINE __device__ __forceinline__

typedef short bf16x8 __attribute__((ext_vector_type(8)));
typedef float f32x4  __attribute__((ext_vector_type(4)));

static constexpr int Bb = 4, Nn = 4096, Dd = 1024, Hh = 16, DHd = 64;
static constexpr int Mrows = Bb * Nn;   // 16384

DEV_INLINE float bf2f(short s) {
  unsigned u = ((unsigned)(unsigned short)s) << 16;
  float f; __builtin_memcpy(&f, &u, 4); return f;
}
DEV_INLINE short f2bf(float f) {
  unsigned u; __builtin_memcpy(&u, &f, 4);
  unsigned r = (u + 0x7fffu + ((u >> 16) & 1u)) >> 16;
  return (short)r;
}

DEV_INLINE void gload16(const void* g, void* l) {
  typedef __attribute__((address_space(1))) const void gv_t;
  typedef __attribute__((address_space(3))) void lv_t;
  __builtin_amdgcn_global_load_lds((gv_t*)g, (lv_t*)l, 16, 0, 0);
}

// swizzled LDS offset (shorts) for the 128x128 bf16 epilogue tile
DEV_INLINE int lds_off(int r_, int c_) {
  return r_ * 128 + ((((c_ >> 3) ^ (r_ & 7)) << 3) | (c_ & 7));
}

// ---------------- 1. conversions ----------------

__global__ void convert_x_kernel(const float* __restrict__ x, short* __restrict__ xb) {
  const int total = Mrows * 1024 / 4;
  for (int i = blockIdx.x * 256 + threadIdx.x; i < total; i += 2048 * 256) {
    float4 v = ((const float4*)x)[i];
    short4 o;
    o.x = f2bf(v.x); o.y = f2bf(v.y); o.z = f2bf(v.z); o.w = f2bf(v.w);
    ((short4*)xb)[i] = o;
  }
}

// W: [1024][1024] fp32 row-major [k][n] -> Wt: [n][k] bf16 ; z selects which W.
// Also zero-inits ksum (runs before gemm128<0> on the stream).
__global__ void transposeW_kernel(const float* __restrict__ Wq, const float* __restrict__ Wk,
                                  const float* __restrict__ Wv, const float* __restrict__ Wo,
                                  short* __restrict__ Wt, short* __restrict__ WoT,
                                  float* __restrict__ ksum) {
  int z = blockIdx.z;
  int t = threadIdx.x;
  if (z == 0 && blockIdx.y == 0 && blockIdx.x < 16)
    ksum[blockIdx.x * 256 + t] = 0.f;            // 64*64 floats
  const float* W = (z == 0) ? Wq : (z == 1) ? Wk : (z == 2) ? Wv : Wo;
  short* dstb = (z < 3) ? (Wt + (size_t)z * 1024 * 1024) : WoT;
  __shared__ float tile[64][69];
  int r = t >> 2, c4 = (t & 3) << 4;
  const float* src = W + (blockIdx.y * 64 + r) * 1024 + blockIdx.x * 64 + c4;
  for (int j = 0; j < 4; ++j) {
    float4 v = ((const float4*)src)[j];
    tile[r][c4 + 4 * j + 0] = v.x;
    tile[r][c4 + 4 * j + 1] = v.y;
    tile[r][c4 + 4 * j + 2] = v.z;
    tile[r][c4 + 4 * j + 3] = v.w;
  }
  __syncthreads();
  __attribute__((aligned(16))) short tmp[16];
  for (int j = 0; j < 16; ++j) tmp[j] = f2bf(tile[c4 + j][r]);
  short* dst = dstb + (blockIdx.x * 64 + r) * 1024 + blockIdx.y * 64 + c4;
  ((int4*)dst)[0] = ((int4*)tmp)[0];
  ((int4*)dst)[1] = ((int4*)tmp)[1];
}

// ---------------- 2/5. 128x128 bf16 MFMA GEMM ----------------
// XCD-contiguous mapping; K-loop LDS XOR-swizzled (linear gload_lds dest +
// pre-swizzled global source slot + same XOR on ds_read — rule #21).
template <int MODE>
__global__ __launch_bounds__(256, 4) void gemm128_kernel(
    const short* __restrict__ A, const short* __restrict__ Bt,
    short* __restrict__ q, short* __restrict__ kT, short* __restrict__ vT,
    float* __restrict__ out, const float* __restrict__ bias,
    float* __restrict__ ksum, int nTilesN) {
  __shared__ __align__(16) short sm[128 * 128];   // K-loop: A | B halves; epilogue: C tile
  short* smA = sm;
  short* smB = sm + 8192;
  const int K = 1024;
  int bid0 = blockIdx.x;
  int xcd = bid0 & 7, local = bid0 >> 3;
  int chunk = local >> 6, rem = local & 63;       // 64 blocks per 8x8 chunk
  int ncc = nTilesN >> 3;
  int cm = chunk / ncc, cn = chunk % ncc;
  int tm = xcd * 16 + cm * 8 + (rem >> 3);
  int tn = cn * 8 + (rem & 7);

  int t = threadIdx.x, w = t >> 6, lane = t & 63;
  int rl = lane & 15, kg = lane >> 4;
  int wr = w >> 1, wc = w & 1;
  const short* Abase = A + (size_t)tm * 128 * K;
  const short* Bbase = Bt + (size_t)tn * 128 * K;

  f32x4 acc[4][4] = {};
  for (int k0 = 0; k0 < K; k0 += 64) {
    __syncthreads();
    for (int p = 0; p < 4; ++p) {
      int c = p * 256 + t;
      int row = c >> 3, u = c & 7;
      int off = ((u ^ (row & 7)) << 3);           // pre-swizzled source slot
      gload16(Abase + row * K + k0 + off, (char*)smA + p * 4096 + w * 1024);
      gload16(Bbase + row * K + k0 + off, (char*)smB + p * 4096 + w * 1024);
    }
    __syncthreads();
    for (int kk = 0; kk < 2; ++kk) {
      int slot = kk * 4 + kg;                     // kb>>3
      bf16x8 af[4], bfr[4];
      for (int mt = 0; mt < 4; ++mt) {
        int row = wr * 64 + mt * 16 + rl;
        af[mt] = *(const bf16x8*)&smA[row * 64 + ((slot ^ (row & 7)) << 3)];
      }
      for (int nt = 0; nt < 4; ++nt) {
        int row = wc * 64 + nt * 16 + rl;
        bfr[nt] = *(const bf16x8*)&smB[row * 64 + ((slot ^ (row & 7)) << 3)];
      }
      for (int mt = 0; mt < 4; ++mt)
        for (int nt = 0; nt < 4; ++nt)
          acc[mt][nt] = __builtin_amdgcn_mfma_f32_16x16x32_bf16(af[mt], bfr[nt], acc[mt][nt], 0, 0, 0);
    }
  }
  // C/D layout: col = lane&15, row = 4*(lane>>4)+reg
  if (MODE == 1) {
    // LDS-staged fp32 epilogue, two 64-row half-passes, coalesced float4 stores
    float* smf = (float*)sm;                      // 64 x 128 fp32 = 32 KB
    __syncthreads();
    for (int h = 0; h < 2; ++h) {
      if (wr == h) {
        for (int mt = 0; mt < 4; ++mt)
          for (int nt = 0; nt < 4; ++nt)
            for (int r = 0; r < 4; ++r)
              smf[(mt * 16 + kg * 4 + r) * 128 + wc * 64 + nt * 16 + rl] = acc[mt][nt][r];
      }
      __syncthreads();
      for (int i = 0; i < 8; ++i) {
        int idx = i * 256 + t;
        int row = idx >> 5, c4 = (idx & 31) << 2;
        float4 v = *(const float4*)&smf[row * 128 + c4];
        float4 bv = *(const float4*)&bias[tn * 128 + c4];
        v.x += bv.x; v.y += bv.y; v.z += bv.z; v.w += bv.w;
        *(float4*)&out[(size_t)(tm * 128 + h * 64 + row) * Dd + tn * 128 + c4] = v;
      }
      __syncthreads();
    }
    return;
  }
  // MODE 0: stage C tile in LDS (transposed for k/v), then coalesced int4 stores
  __syncthreads();
  int sec = tn >> 3;                     // 0=q 1=k 2=v (128-col tiles never straddle)
  int tloc = tn & 7;
  for (int mt = 0; mt < 4; ++mt)
    for (int nt = 0; nt < 4; ++nt)
      for (int r = 0; r < 4; ++r) {
        float v = acc[mt][nt][r];
        if (sec <= 1) v = v > 0.f ? v + 1.f : __expf(v);   // elu(x)+1
        int row = wr * 64 + mt * 16 + kg * 4 + r;
        int col = wc * 64 + nt * 16 + rl;
        int o = (sec == 0) ? lds_off(row, col) : lds_off(col, row);
        sm[o] = f2bf(v);
      }
  __syncthreads();
  if (sec == 0) {
    for (int i = 0; i < 8; ++i) {
      int idx = i * 256 + t;
      int row = idx >> 4, c = idx & 15;
      int col0 = c * 8;
      int gcol = tloc * 128 + col0;
      int h = gcol >> 6, d0 = gcol & 63;
      int grow = tm * 128 + row;
      int b = grow >> 12, n = grow & 4095;
      *(int4*)&q[(((size_t)(b * Hh + h)) * Nn + n) * DHd + d0] = *(const int4*)&sm[lds_off(row, col0)];
    }
  } else {
    short* dst = (sec == 1) ? kT : vT;
    for (int i = 0; i < 8; ++i) {
      int idx = i * 256 + t;
      int dcol = idx >> 4, c = idx & 15;
      int n0 = c * 8;
      int gcol = tloc * 128 + dcol;
      int h = gcol >> 6, d = gcol & 63;
      int grow0 = tm * 128 + n0;
      int b = grow0 >> 12, n = grow0 & 4095;
      *(int4*)&dst[(((size_t)(b * Hh + h)) * DHd + d) * Nn + n] = *(const int4*)&sm[lds_off(dcol, n0)];
    }
    if (sec == 1) {
      // fused ksum: sum the staged k-tile (layout [dcol][n], swizzled) over n
      int dcol = t >> 1, half = t & 1;
      float s = 0.f;
      for (int c = half * 64; c < half * 64 + 64; ++c)
        s += bf2f(sm[lds_off(dcol, c)]);
      s += __shfl_xor(s, 1);
      if (half == 0) {
        int g = tloc * 128 + dcol;
        int h = g >> 6, d = g & 63;
        int b = (tm * 128) >> 12;
        atomicAdd(&ksum[(b * Hh + h) * DHd + d], s);
      }
    }
  }
}

// ---------------- 3. kv partials: kvp[bh][8][e][d] fp32 ----------------
__global__ __launch_bounds__(256, 2) void kv_kernel(const short* __restrict__ kT,
                                                    const short* __restrict__ vT,
                                                    float* __restrict__ kvp) {
  __shared__ __align__(16) short smK[64 * 128];
  __shared__ __align__(16) short smV[64 * 128];
  int bh = blockIdx.x, seg = blockIdx.y;
  int t = threadIdx.x;
  int w = t >> 6, lane = t & 63, rl = lane & 15, kg = lane >> 4;
  const short* kb = kT + (size_t)bh * DHd * Nn + seg * 512;
  const short* vb = vT + (size_t)bh * DHd * Nn + seg * 512;
  f32x4 acc[4] = {};
  for (int n0 = 0; n0 < 512; n0 += 128) {
    __syncthreads();
    for (int p = 0; p < 4; ++p) {
      int c = p * 256 + t;
      int row = c >> 4, u = c & 15;
      int off = ((u ^ (row & 15)) << 3);          // pre-swizzled source slot
      gload16(kb + row * Nn + n0 + off, (char*)smK + p * 4096 + w * 1024);
      gload16(vb + row * Nn + n0 + off, (char*)smV + p * 4096 + w * 1024);
    }
    __syncthreads();
    for (int kk = 0; kk < 4; ++kk) {
      int slot = kk * 4 + kg;
      int rowA = w * 16 + rl;
      bf16x8 a = *(const bf16x8*)&smK[rowA * 128 + ((slot ^ (rowA & 15)) << 3)];
      for (int nt = 0; nt < 4; ++nt) {
        int rowB = nt * 16 + rl;
        bf16x8 b = *(const bf16x8*)&smV[rowB * 128 + ((slot ^ (rowB & 15)) << 3)];
        acc[nt] = __builtin_amdgcn_mfma_f32_16x16x32_bf16(a, b, acc[nt], 0, 0, 0);
      }
    }
  }
  // LDS-staged coalesced fp32 output (64x64 tile = 16 KB, reuse smK)
  float* smf = (float*)smK;
  __syncthreads();
  for (int nt = 0; nt < 4; ++nt)
    for (int r = 0; r < 4; ++r)
      smf[(nt * 16 + rl) * 64 + (w * 16 + kg * 4 + r)] = acc[nt][r];
  __syncthreads();
  float* dst = kvp + ((size_t)(bh * 8 + seg)) * 4096;
  for (int i = 0; i < 4; ++i) {
    int idx = i * 256 + t;
    int e = idx >> 4, c4 = (idx & 15) << 2;
    *(float4*)&dst[e * 64 + c4] = *(const float4*)&smf[e * 64 + c4];
  }
}

// combine 8 fp32 partials -> kvT bf16 [bh][e][d]
__global__ void kvc_kernel(const float* __restrict__ kvp, short* __restrict__ kvT) {
  int bh = blockIdx.x, t = threadIdx.x;
  const float* p0 = kvp + (size_t)bh * 8 * 4096;
  for (int rep = 0; rep < 4; ++rep) {
    int idx = rep * 1024 + t * 4;
    float4 s = *(const float4*)&p0[idx];
    for (int j = 1; j < 8; ++j) {
      float4 a = *(const float4*)&p0[j * 4096 + idx];
      s.x += a.x; s.y += a.y; s.z += a.z; s.w += a.w;
    }
    short4 o;
    o.x = f2bf(s.x); o.y = f2bf(s.y); o.z = f2bf(s.z); o.w = f2bf(s.w);
    *(short4*)&kvT[(size_t)bh * 4096 + idx] = o;
  }
}

// ---------------- 4. out = (q @ kv) / z ----------------
__global__ __launch_bounds__(256, 2) void attn_kernel(const short* __restrict__ q,
                                                      const short* __restrict__ kvT,
                                                      const float* __restrict__ ksum,
                                                      short* __restrict__ attn) {
  int rb = blockIdx.x, bh = blockIdx.y;
  int b = bh >> 4, h = bh & 15;
  __shared__ float sks[64];
  __shared__ __align__(16) short satt[64 * 64];
  int t = threadIdx.x, w = t >> 6, lane = t & 63, rl = lane & 15, kg = lane >> 4;
  if (t < 64) sks[t] = ksum[bh * 64 + t];
  __syncthreads();
  int row0 = rb * 64 + w * 16;
  const short* qb = q + ((size_t)bh * Nn + row0) * DHd;
  const short* kvb = kvT + (size_t)bh * 4096;
  f32x4 acc[4] = {};
  float zp = 0.f;
  for (int kk = 0; kk < 2; ++kk) {
    int kb = kk * 32 + kg * 8;
    bf16x8 a = *(const bf16x8*)&qb[rl * DHd + kb];
    for (int j = 0; j < 8; ++j) zp += bf2f(a[j]) * sks[kb + j];
    for (int nt = 0; nt < 4; ++nt) {
      bf16x8 bfr = *(const bf16x8*)&kvb[(nt * 16 + rl) * 64 + kb];
      acc[nt] = __builtin_amdgcn_mfma_f32_16x16x32_bf16(a, bfr, acc[nt], 0, 0, 0);
    }
  }
  zp += __shfl_xor(zp, 16);
  zp += __shfl_xor(zp, 32);     // every lane now holds z for row (lane&15)
  float zr[4];
  for (int r = 0; r < 4; ++r) zr[r] = __shfl(zp, kg * 4 + r);
  for (int nt = 0; nt < 4; ++nt)
    for (int r = 0; r < 4; ++r)
      satt[(w * 16 + kg * 4 + r) * 64 + nt * 16 + rl] = f2bf(acc[nt][r] / (zr[r] + 1e-6f));
  __syncthreads();
  for (int i = 0; i < 2; ++i) {
    int idx = i * 256 + t;                 // int4 index over 64x64 shorts
    int row = idx >> 3, c8 = (idx & 7) << 3;
    int n = rb * 64 + row;
    *(int4*)&attn[((size_t)(b * Nn + n)) * 1024 + h * 64 + c8] = *(const int4*)&satt[row * 64 + c8];
  }
}

// ---------------- launch ----------------
extern "C" void kernel_launch(void* const* d_in, const int* in_sizes, int n_in,
                              void* d_out, int out_size, void* d_ws, size_t ws_size,
                              hipStream_t stream) {
  const float* x  = (const float*)d_in[0];
  const float* Wq = (const float*)d_in[1];
  const float* Wk = (const float*)d_in[2];
  const float* Wv = (const float*)d_in[3];
  const float* Wo = (const float*)d_in[4];
  const float* bo = (const float*)d_in[5];
  float* out = (float*)d_out;

  char* ws = (char*)d_ws;
  size_t off = 0;
  auto alloc = [&](size_t bytes) {
    char* p = ws + off;
    off += (bytes + 255) & ~(size_t)255;
    return p;
  };
  short* xb   = (short*)alloc((size_t)Mrows * 1024 * 2);     // 32 MB
  short* Wt   = (short*)alloc((size_t)3072 * 1024 * 2);      // 6 MB
  short* WoT  = (short*)alloc((size_t)1024 * 1024 * 2);      // 2 MB
  short* qb   = (short*)alloc((size_t)64 * Nn * DHd * 2);    // 32 MB  [bh][n][d]
  short* kT   = (short*)alloc((size_t)64 * DHd * Nn * 2);    // 32 MB  [bh][d][n]
  short* vT   = (short*)alloc((size_t)64 * DHd * Nn * 2);    // 32 MB  [bh][d][n]
  float* ksum = (float*)alloc((size_t)64 * 64 * 4);          // fused ksum accumulator
  float* kvp  = (float*)alloc((size_t)64 * 8 * 4096 * 4);    // 8 MB kv partials
  short* kvT  = (short*)alloc((size_t)64 * 4096 * 2);        // [bh][e][d]
  short* attn = (short*)alloc((size_t)Mrows * 1024 * 2);     // 32 MB

  convert_x_kernel<<<2048, 256, 0, stream>>>(x, xb);
  transposeW_kernel<<<dim3(16, 16, 4), 256, 0, stream>>>(Wq, Wk, Wv, Wo, Wt, WoT, ksum);

  gemm128_kernel<0><<<3072, 256, 0, stream>>>(xb, Wt, qb, kT, vT, nullptr, nullptr, ksum, 24);
  kv_kernel<<<dim3(64, 8), 256, 0, stream>>>(kT, vT, kvp);
  kvc_kernel<<<64, 256, 0, stream>>>(kvp, kvT);
  attn_kernel<<<dim3(64, 64), 256, 0, stream>>>(qb, kvT, ksum, attn);
  gemm128_kernel<1><<<1024, 256, 0, stream>>>(attn, WoT, nullptr, nullptr, nullptr, out, bo, nullptr, 8);
}